// Round 3
// baseline (201.314 us; speedup 1.0000x reference)
//
#include <hip/hip_runtime.h>

#define TT 3
#define CCH 32
#define HH 256
#define WW 256
#define KK 7
#define NQ 64
#define QPB 16
#define V1W 80
#define V1N (14*V1W)      // 1120 floats per channel plane
#define V1P (V1N + 8)     // 1128 (mod 32 == 8)
#define V0W 72
#define V0N (7*V0W)       // 504
#define V0P (V0N + 16)    // 520 (mod 32 == 8)
#define CHC 4             // channels per chunk
#define NCHUNK 4          // 16 channels per block

__device__ __forceinline__ int refl(int i, int n) {
    i = i < 0 ? -i : i;
    return i >= n ? 2*(n-1) - i : i;
}

// ---------------- kernel 1: partial dists (16 channels per block) ----------
__global__ __launch_bounds__(256, 6)
void nls_partial(const float* __restrict__ vid0, const float* __restrict__ vid1,
                 float* __restrict__ ws) {
    __shared__ float v1s[CHC * V1P];   // 18048 B
    __shared__ float v0s[CHC * V0P];   // 8320 B  -> 26368 B (6 blocks/CU)

    const int bx   = blockIdx.x;
    const int half = bx & 1;
    const int b2   = bx >> 1;
    const int t    = b2 >> 8;
    const int rem  = b2 & 255;
    const int qy   = rem >> 2;
    const int q0   = (rem & 3) * QPB;
    const int qh   = qy * 4;
    const int w0   = 4*q0 - 7;

    const int tid   = threadIdx.x;
    const int qwi   = tid & 15;
    const int clane = (tid >> 4) & 3;
    const int shq   = tid >> 6;

    // per-thread staging offsets (channel-independent)
    int off1[5];
#pragma unroll
    for (int k = 0; k < 5; ++k) {
        int idx = tid + 256*k;
        if (idx < V1N) {
            int r = idx / V1W, wi = idx - r*V1W;
            off1[k] = refl(qh + r - 7, HH) * WW + refl(w0 + wi, WW);
        } else off1[k] = 0;
    }
    int off0[2];
#pragma unroll
    for (int k = 0; k < 2; ++k) {
        int idx = tid + 256*k;
        if (idx < V0N) {
            int r = idx / V0W, wi = idx - r*V0W;
            off0[k] = refl(qh + r - 3, HH) * WW + refl(w0 + wi, WW);
        } else off0[k] = 0;
    }

    const float* g0 = vid0 + ((size_t)t*CCH + half*16) * (HH*WW);
    const float* g1 = vid1 + ((size_t)t*CCH + half*16) * (HH*WW);

    float acc[2][8];
#pragma unroll
    for (int l = 0; l < 2; ++l)
#pragma unroll
        for (int b = 0; b < 8; ++b) acc[l][b] = 0.f;

    float t1[CHC][5];
    float t0v[CHC][2];

    auto load_chunk = [&](int s) {
        const int cb = CHC * s * (HH*WW);
#pragma unroll
        for (int ch = 0; ch < CHC; ++ch) {
            const float* p1 = g1 + cb + ch*(HH*WW);
            const float* p0 = g0 + cb + ch*(HH*WW);
#pragma unroll
            for (int k = 0; k < 4; ++k) t1[ch][k] = p1[off1[k]];
            t1[ch][4]  = (tid < V1N - 1024) ? p1[off1[4]] : 0.f;
            t0v[ch][0] = p0[off0[0]];
            t0v[ch][1] = (tid < V0N - 256) ? p0[off0[1]] : 0.f;
        }
    };

    load_chunk(0);

#pragma unroll 1
    for (int s = 0; s < NCHUNK; ++s) {
        // regs -> LDS
#pragma unroll
        for (int ch = 0; ch < CHC; ++ch) {
#pragma unroll
            for (int k = 0; k < 4; ++k) v1s[ch*V1P + tid + 256*k] = t1[ch][k];
            if (tid < V1N - 1024) v1s[ch*V1P + tid + 1024] = t1[ch][4];
            v0s[ch*V0P + tid] = t0v[ch][0];
            if (tid < V0N - 256) v0s[ch*V0P + tid + 256] = t0v[ch][1];
        }
        __syncthreads();

        if (s + 1 < NCHUNK) load_chunk(s + 1);   // overlaps compute below

        // ---- compute ----
        float x[7][8];
        const float* xb = &v0s[clane*V0P + 4*qwi + 4];
#pragma unroll
        for (int i = 0; i < 7; ++i) {
            float4 a = *(const float4*)(xb + i*V0W);
            float4 b = *(const float4*)(xb + i*V0W + 4);
            x[i][0]=a.x; x[i][1]=a.y; x[i][2]=a.z; x[i][3]=a.w;
            x[i][4]=b.x; x[i][5]=b.y; x[i][6]=b.z; x[i][7]=b.w;
        }
        const float* yb = &v1s[clane*V1P + (2*shq)*V1W + 4*qwi];
#pragma unroll
        for (int rr = 0; rr < 8; ++rr) {
            const float4* py = (const float4*)(yb + rr*V1W);
            float4 A = py[0], B = py[1], C = py[2], D = py[3];
            float y[16];
            y[0]=A.x;  y[1]=A.y;  y[2]=A.z;  y[3]=A.w;
            y[4]=B.x;  y[5]=B.y;  y[6]=B.z;  y[7]=B.w;
            y[8]=C.x;  y[9]=C.y;  y[10]=C.z; y[11]=C.w;
            y[12]=D.x; y[13]=D.y; y[14]=D.z; y[15]=D.w;
            if (rr < 7) {
#pragma unroll
                for (int sw = 0; sw < 8; ++sw)
#pragma unroll
                    for (int j = 0; j < 7; ++j)
                        acc[0][sw] += x[rr][j] * y[sw + j];
            }
            if (rr >= 1) {
#pragma unroll
                for (int sw = 0; sw < 8; ++sw)
#pragma unroll
                    for (int j = 0; j < 7; ++j)
                        acc[1][sw] += x[rr-1][j] * y[sw + j];
            }
        }
        __syncthreads();
    }

    // reduce across 4 channel lanes
#pragma unroll
    for (int m = 16; m <= 32; m <<= 1)
#pragma unroll
        for (int l = 0; l < 2; ++l)
#pragma unroll
            for (int b = 0; b < 8; ++b)
                acc[l][b] += __shfl_xor(acc[l][b], m, 64);

    float* dlds = v1s;   // overlay: 16 q x 64 shifts
    if (clane == 0) {
#pragma unroll
        for (int l = 0; l < 2; ++l)
#pragma unroll
            for (int b = 0; b < 8; ++b)
                dlds[qwi*64 + (2*shq + l)*8 + b] = acc[l][b];
    }
    __syncthreads();

    float* wp = ws + (size_t)bx * 1024;
    for (int i = tid; i < 1024; i += 256) wp[i] = dlds[i];
}

// ---------------- kernel 2: combine halves + top-7 -------------------------
__global__ __launch_bounds__(256, 4)
void nls_topk(const float* __restrict__ ws, float* __restrict__ out) {
    __shared__ float dlds[QPB * 64];
    const int p   = blockIdx.x;
    const int t   = p >> 8;
    const int rem = p & 255;
    const int qy  = rem >> 2;
    const int q0  = (rem & 3) * QPB;
    const int qh  = qy * 4;
    const int tid = threadIdx.x;

    const float* a = ws + (size_t)p * 2048;
    for (int i = tid; i < 1024; i += 256) dlds[i] = a[i] + a[i + 1024];
    __syncthreads();

    const int q16 = tid >> 4;
    const int l16 = tid & 15;
    const float* d = &dlds[q16 * 64];
    const int j0 = l16 * 4;
    float cv[4];
#pragma unroll
    for (int jj = 0; jj < 4; ++jj) {
        float v = d[j0 + jj];
        if (j0 + jj == 36) v += 1e30f;    // self bias (selection only)
        cv[jj] = v;
    }
    unsigned mask = 0;
    const int qx = q0 + q16;
    const int q  = (t*NQ + qy)*NQ + qx;
    float* od = out + q*KK;
    float* oi = out + (size_t)TT*NQ*NQ*KK + (size_t)q*KK*3;
    for (int k = 0; k < KK; ++k) {
        float best = -3.4e38f; int bi = 1 << 30;
#pragma unroll
        for (int jj = 0; jj < 4; ++jj)
            if (!(mask & (1u << jj)) && cv[jj] > best) { best = cv[jj]; bi = j0 + jj; }
#pragma unroll
        for (int m = 1; m <= 8; m <<= 1) {
            float ob = __shfl_xor(best, m, 64);
            int  obi = __shfl_xor(bi,  m, 64);
            if (ob > best || (ob == best && obi < bi)) { best = ob; bi = obi; }
        }
        if ((bi >> 2) == l16) mask |= 1u << (bi & 3);
        if (l16 == 0) {
            od[k] = d[bi];                 // unbiased value
            int dh = (bi >> 3) - 4;
            int dw = (bi & 7) - 4;
            oi[k*3 + 0] = (float)t;
            oi[k*3 + 1] = (float)refl(qh + dh, HH);
            oi[k*3 + 2] = (float)refl(qx*4 + dw, WW);
        }
    }
}

extern "C" void kernel_launch(void* const* d_in, const int* in_sizes, int n_in,
                              void* d_out, int out_size, void* d_ws, size_t ws_size,
                              hipStream_t stream) {
    (void)in_sizes; (void)n_in; (void)ws_size; (void)out_size;
    const float* vid0 = (const float*)d_in[0];
    const float* vid1 = (const float*)d_in[1];
    float* out = (float*)d_out;
    float* ws  = (float*)d_ws;   // needs 1536*1024*4 = 6.29 MB
    nls_partial<<<dim3(2 * TT * NQ * (NQ / QPB)), dim3(256), 0, stream>>>(vid0, vid1, ws);
    nls_topk<<<dim3(TT * NQ * (NQ / QPB)), dim3(256), 0, stream>>>(ws, out);
}

// Round 4
// 138.042 us; speedup vs baseline: 1.4583x; 1.4583x over previous
//
#include <hip/hip_runtime.h>

#define TT 3
#define CCH 32
#define HH 256
#define WW 256
#define KK 7
#define NQ 64
#define QPB 16
#define V1W 80
#define V1N (14*V1W)      // 1120 floats per channel plane
#define V1P (V1N + 8)     // 1128 (mod 32 == 8)
#define V0W 72
#define V0N (7*V0W)       // 504
#define V0P (V0N + 16)    // 520 (mod 32 == 8)
#define CHC 4             // channels per chunk
#define NCHUNK 4          // 16 channels per block (half split)

__device__ __forceinline__ int refl(int i, int n) {
    i = i < 0 ? -i : i;
    return i >= n ? 2*(n-1) - i : i;
}

// ---------------- kernel 1: partial dists (16 channels per block) ----------
__global__ __launch_bounds__(256, 6)
void nls_partial(const float* __restrict__ vid0, const float* __restrict__ vid1,
                 float* __restrict__ ws) {
    __shared__ float v1s[CHC * V1P];   // 18048 B
    __shared__ float v0s[CHC * V0P];   // 8320 B  -> 26368 B (6 blocks/CU)

    const int bx   = blockIdx.x;
    const int half = bx & 1;
    const int b2   = bx >> 1;
    const int t    = b2 >> 8;
    const int rem  = b2 & 255;
    const int qy   = rem >> 2;
    const int q0   = (rem & 3) * QPB;
    const int qh   = qy * 4;
    const int w0   = 4*q0 - 7;

    const int tid   = threadIdx.x;
    const int qwi   = tid & 15;
    const int clane = (tid >> 4) & 3;
    const int shq   = tid >> 6;

    // per-thread staging offsets (channel-independent)
    int off1[5];
#pragma unroll
    for (int k = 0; k < 5; ++k) {
        int idx = tid + 256*k;
        if (idx < V1N) {
            int r = idx / V1W, wi = idx - r*V1W;
            off1[k] = refl(qh + r - 7, HH) * WW + refl(w0 + wi, WW);
        } else off1[k] = 0;
    }
    int off0[2];
#pragma unroll
    for (int k = 0; k < 2; ++k) {
        int idx = tid + 256*k;
        if (idx < V0N) {
            int r = idx / V0W, wi = idx - r*V0W;
            off0[k] = refl(qh + r - 3, HH) * WW + refl(w0 + wi, WW);
        } else off0[k] = 0;
    }

    const float* g0 = vid0 + ((size_t)t*CCH + half*16) * (HH*WW);
    const float* g1 = vid1 + ((size_t)t*CCH + half*16) * (HH*WW);

    float acc[2][8];
#pragma unroll
    for (int l = 0; l < 2; ++l)
#pragma unroll
        for (int b = 0; b < 8; ++b) acc[l][b] = 0.f;

#pragma unroll 1
    for (int s = 0; s < NCHUNK; ++s) {
        const int cb = CHC * s * (HH*WW);
        __syncthreads();
        // ---- stage: load to regs, then LDS (short-lived temps, no spill) ----
        float t1[CHC][5];
        float t0v[CHC][2];
#pragma unroll
        for (int ch = 0; ch < CHC; ++ch) {
            const float* p1 = g1 + cb + ch*(HH*WW);
            const float* p0 = g0 + cb + ch*(HH*WW);
#pragma unroll
            for (int k = 0; k < 4; ++k) t1[ch][k] = p1[off1[k]];
            t1[ch][4]  = (tid < V1N - 1024) ? p1[off1[4]] : 0.f;
            t0v[ch][0] = p0[off0[0]];
            t0v[ch][1] = (tid < V0N - 256) ? p0[off0[1]] : 0.f;
        }
#pragma unroll
        for (int ch = 0; ch < CHC; ++ch) {
#pragma unroll
            for (int k = 0; k < 4; ++k) v1s[ch*V1P + tid + 256*k] = t1[ch][k];
            if (tid < V1N - 1024) v1s[ch*V1P + tid + 1024] = t1[ch][4];
            v0s[ch*V0P + tid] = t0v[ch][0];
            if (tid < V0N - 256) v0s[ch*V0P + tid + 256] = t0v[ch][1];
        }
        __syncthreads();

        // ---- compute: my channel = 4s + clane (+ half*16) ----
        float x[7][8];
        const float* xb = &v0s[clane*V0P + 4*qwi + 4];
#pragma unroll
        for (int i = 0; i < 7; ++i) {
            float4 a = *(const float4*)(xb + i*V0W);
            float4 b = *(const float4*)(xb + i*V0W + 4);
            x[i][0]=a.x; x[i][1]=a.y; x[i][2]=a.z; x[i][3]=a.w;
            x[i][4]=b.x; x[i][5]=b.y; x[i][6]=b.z; x[i][7]=b.w;
        }
        const float* yb = &v1s[clane*V1P + (2*shq)*V1W + 4*qwi];
#pragma unroll
        for (int rr = 0; rr < 8; ++rr) {
            const float4* py = (const float4*)(yb + rr*V1W);
            float4 A = py[0], B = py[1], C = py[2], D = py[3];
            float y[16];
            y[0]=A.x;  y[1]=A.y;  y[2]=A.z;  y[3]=A.w;
            y[4]=B.x;  y[5]=B.y;  y[6]=B.z;  y[7]=B.w;
            y[8]=C.x;  y[9]=C.y;  y[10]=C.z; y[11]=C.w;
            y[12]=D.x; y[13]=D.y; y[14]=D.z; y[15]=D.w;
            if (rr < 7) {
#pragma unroll
                for (int sw = 0; sw < 8; ++sw)
#pragma unroll
                    for (int j = 0; j < 7; ++j)
                        acc[0][sw] += x[rr][j] * y[sw + j];
            }
            if (rr >= 1) {
#pragma unroll
                for (int sw = 0; sw < 8; ++sw)
#pragma unroll
                    for (int j = 0; j < 7; ++j)
                        acc[1][sw] += x[rr-1][j] * y[sw + j];
            }
        }
    }

    // reduce across 4 channel lanes (intra-wave bits 4,5)
#pragma unroll
    for (int m = 16; m <= 32; m <<= 1)
#pragma unroll
        for (int l = 0; l < 2; ++l)
#pragma unroll
            for (int b = 0; b < 8; ++b)
                acc[l][b] += __shfl_xor(acc[l][b], m, 64);

    __syncthreads();                 // all v1s reads done; overlay dists
    float* dlds = v1s;               // 16 q x 64 shifts
    if (clane == 0) {
#pragma unroll
        for (int l = 0; l < 2; ++l)
#pragma unroll
            for (int b = 0; b < 8; ++b)
                dlds[qwi*64 + (2*shq + l)*8 + b] = acc[l][b];
    }
    __syncthreads();

    float* wp = ws + (size_t)bx * 1024;
    for (int i = tid; i < 1024; i += 256) wp[i] = dlds[i];
}

// ---------------- kernel 2: combine halves + top-7 -------------------------
__global__ __launch_bounds__(256, 4)
void nls_topk(const float* __restrict__ ws, float* __restrict__ out) {
    __shared__ float dlds[QPB * 64];
    const int p   = blockIdx.x;
    const int t   = p >> 8;
    const int rem = p & 255;
    const int qy  = rem >> 2;
    const int q0  = (rem & 3) * QPB;
    const int qh  = qy * 4;
    const int tid = threadIdx.x;

    const float* a = ws + (size_t)p * 2048;
    for (int i = tid; i < 1024; i += 256) dlds[i] = a[i] + a[i + 1024];
    __syncthreads();

    const int q16 = tid >> 4;
    const int l16 = tid & 15;
    const float* d = &dlds[q16 * 64];
    const int j0 = l16 * 4;
    float cv[4];
#pragma unroll
    for (int jj = 0; jj < 4; ++jj) {
        float v = d[j0 + jj];
        if (j0 + jj == 36) v += 1e30f;    // self bias (selection only)
        cv[jj] = v;
    }
    unsigned mask = 0;
    const int qx = q0 + q16;
    const int q  = (t*NQ + qy)*NQ + qx;
    float* od = out + q*KK;
    float* oi = out + (size_t)TT*NQ*NQ*KK + (size_t)q*KK*3;
    for (int k = 0; k < KK; ++k) {
        float best = -3.4e38f; int bi = 1 << 30;
#pragma unroll
        for (int jj = 0; jj < 4; ++jj)
            if (!(mask & (1u << jj)) && cv[jj] > best) { best = cv[jj]; bi = j0 + jj; }
#pragma unroll
        for (int m = 1; m <= 8; m <<= 1) {
            float ob = __shfl_xor(best, m, 64);
            int  obi = __shfl_xor(bi,  m, 64);
            if (ob > best || (ob == best && obi < bi)) { best = ob; bi = obi; }
        }
        if ((bi >> 2) == l16) mask |= 1u << (bi & 3);
        if (l16 == 0) {
            od[k] = d[bi];                 // unbiased value
            int dh = (bi >> 3) - 4;
            int dw = (bi & 7) - 4;
            oi[k*3 + 0] = (float)t;
            oi[k*3 + 1] = (float)refl(qh + dh, HH);
            oi[k*3 + 2] = (float)refl(qx*4 + dw, WW);
        }
    }
}

extern "C" void kernel_launch(void* const* d_in, const int* in_sizes, int n_in,
                              void* d_out, int out_size, void* d_ws, size_t ws_size,
                              hipStream_t stream) {
    (void)in_sizes; (void)n_in; (void)ws_size; (void)out_size;
    const float* vid0 = (const float*)d_in[0];
    const float* vid1 = (const float*)d_in[1];
    float* out = (float*)d_out;
    float* ws  = (float*)d_ws;   // needs 1536*1024*4 = 6.29 MB
    nls_partial<<<dim3(2 * TT * NQ * (NQ / QPB)), dim3(256), 0, stream>>>(vid0, vid1, ws);
    nls_topk<<<dim3(TT * NQ * (NQ / QPB)), dim3(256), 0, stream>>>(ws, out);
}

// Round 5
// 124.394 us; speedup vs baseline: 1.6184x; 1.1097x over previous
//
#include <hip/hip_runtime.h>

#define TT 3
#define CCH 32
#define HH 256
#define WW 256
#define KK 7
#define NQ 64
#define QPB 16
#define V1W 76            // y row length (qwi=15 reads dwords 60..75)
#define V1R 14
#define V1N (V1R*V1W)     // 1064 dwords per channel plane
#define V1P 1080          // pad: 1080 % 32 == 24 -> c01 bank offsets {0,24,16,8}
#define CHC 8             // channels per chunk
#define NCHUNK 4

__device__ __forceinline__ int refl(int i, int n) {
    i = i < 0 ? -i : i;
    return i >= n ? 2*(n-1) - i : i;
}

__device__ __forceinline__ void gload_lds(const float* g, float* l) {
    __builtin_amdgcn_global_load_lds(
        (const __attribute__((address_space(1))) unsigned int*)g,
        (__attribute__((address_space(3))) unsigned int*)l, 4, 0, 0);
}

__global__ __launch_bounds__(256, 3)
void nls_kernel(const float* __restrict__ vid0, const float* __restrict__ vid1,
                float* __restrict__ out) {
    __shared__ float v1s[CHC * V1P];   // 34560 B -> 3 blocks/CU fit easily

    const int bx  = blockIdx.x;
    const int t   = bx >> 8;
    const int rem = bx & 255;
    const int qy  = rem >> 2;
    const int q0  = (rem & 3) * QPB;
    const int qh  = qy * 4;
    const int w0  = 4*q0 - 7;

    const int tid   = threadIdx.x;
    const int qwi   = tid & 15;          // bits 0-3: query (contiguous lanes)
    const int c01   = (tid >> 4) & 3;    // bits 4-5: channel low (intra-wave)
    const int c2    = (tid >> 6) & 1;    // bit 6: channel high (wave)
    const int shh   = tid >> 7;          // bit 7: sh half (wave)
    const int clane = c01 + 4*c2;        // channel 0..7 within chunk
    const int qx    = q0 + qwi;

    // v1 staging offsets (channel-independent, computed once)
    int off1[5];
#pragma unroll
    for (int k = 0; k < 5; ++k) {
        int idx = tid + 256*k;
        if (idx < V1N) {
            int r = idx / V1W, wi = idx - r*V1W;
            off1[k] = refl(qh + r - 7, HH) * WW + refl(w0 + wi, WW);
        } else off1[k] = 0;
    }

    float acc[4][8];
#pragma unroll
    for (int a = 0; a < 4; ++a)
#pragma unroll
        for (int b = 0; b < 8; ++b) acc[a][b] = 0.f;

    const float* g0t = vid0 + (size_t)t * (CCH*HH*WW);
    const float* g1t = vid1 + (size_t)t * (CCH*HH*WW);

#pragma unroll 1
    for (int s = 0; s < NCHUNK; ++s) {
        __syncthreads();   // previous chunk's LDS reads complete before overwrite
        // ---- async DMA: v1 chunk (8 channels) straight into LDS ----
#pragma unroll
        for (int ch = 0; ch < CHC; ++ch) {
            const float* p1 = g1t + (size_t)(CHC*s + ch) * (HH*WW);
            float* lb = &v1s[ch*V1P + (tid & ~63)];
#pragma unroll
            for (int k = 0; k < 4; ++k)
                gload_lds(p1 + off1[k], lb + 256*k);
            if (tid < V1N - 1024)                      // tail: 40 dwords, wave 0
                gload_lds(p1 + off1[4], &v1s[ch*V1P + 1024 + (tid & ~63)]);
        }

        // ---- x patch from global (independent of LDS; overlaps DMA) ----
        const float* p0 = g0t + (size_t)(CHC*s + clane) * (HH*WW);
        float x[7][8];
#pragma unroll
        for (int i = 0; i < 7; ++i) {
            const float* rowp = p0 + refl(qh + i - 3, HH) * WW;
            float4 B = *(const float4*)(rowp + 4*qx);
            float4 A;
            if (qx > 0) A = *(const float4*)(rowp + 4*qx - 4);
            else        A = make_float4(0.f, B.w, B.z, B.y);   // reflect at w<0
            x[i][0]=A.y; x[i][1]=A.z; x[i][2]=A.w;
            x[i][3]=B.x; x[i][4]=B.y; x[i][5]=B.z; x[i][6]=B.w;
        }
        __syncthreads();   // DMA drained (compiler emits vmcnt(0) before barrier)

        // ---- compute: 4 sh x 8 sw per thread, rows L = 4*shh + rr ----
        const float* yb = &v1s[clane*V1P + 4*qwi];
#pragma unroll
        for (int rr = 0; rr < 10; ++rr) {
            const float* yp = yb + (4*shh + rr) * V1W;
            float4 Ya = ((const float4*)yp)[0];
            float4 Yb = ((const float4*)yp)[1];
            float4 Yc = ((const float4*)yp)[2];
            float4 Yd = ((const float4*)yp)[3];
            float y[16];
            y[0]=Ya.x;  y[1]=Ya.y;  y[2]=Ya.z;  y[3]=Ya.w;
            y[4]=Yb.x;  y[5]=Yb.y;  y[6]=Yb.z;  y[7]=Yb.w;
            y[8]=Yc.x;  y[9]=Yc.y;  y[10]=Yc.z; y[11]=Yc.w;
            y[12]=Yd.x; y[13]=Yd.y; y[14]=Yd.z; y[15]=Yd.w;
#pragma unroll
            for (int a = 0; a < 4; ++a) {
                const int pi = rr - a;              // compile-time after unroll
                if (pi >= 0 && pi < 7) {
#pragma unroll
                    for (int sw = 0; sw < 8; ++sw)
#pragma unroll
                        for (int j = 0; j < 7; ++j)
                            acc[a][sw] += x[pi][j] * y[sw + j];
                }
            }
        }
    }

    // ---- reduce over c01 (lane bits 4,5) ----
#pragma unroll
    for (int m = 16; m <= 32; m <<= 1)
#pragma unroll
        for (int a = 0; a < 4; ++a)
#pragma unroll
            for (int b = 0; b < 8; ++b)
                acc[a][b] += __shfl_xor(acc[a][b], m, 64);

    __syncthreads();                 // done with v1s; overlay dists
    float* dlds = v1s;               // [c2][16 q][64 shifts]
    if (c01 == 0) {
#pragma unroll
        for (int a = 0; a < 4; ++a) {
            float* dp = &dlds[c2*1024 + qwi*64 + (shh*4 + a)*8];
            *(float4*)(dp)     = make_float4(acc[a][0], acc[a][1], acc[a][2], acc[a][3]);
            *(float4*)(dp + 4) = make_float4(acc[a][4], acc[a][5], acc[a][6], acc[a][7]);
        }
    }
    __syncthreads();

    // ---- top-7: 16 threads per query ----
    {
        const int q16 = tid >> 4;
        const int l16 = tid & 15;
        const float* d0 = &dlds[q16 * 64];
        const float* d1 = d0 + 1024;
        const int j0 = l16 * 4;
        float cv[4];
#pragma unroll
        for (int jj = 0; jj < 4; ++jj) {
            float v = d0[j0 + jj] + d1[j0 + jj];
            if (j0 + jj == 36) v += 1e30f;    // self bias (selection only)
            cv[jj] = v;
        }
        unsigned mask = 0;
        const int qxx = q0 + q16;
        const int q   = (t*NQ + qy)*NQ + qxx;
        float* od = out + q*KK;
        float* oi = out + (size_t)TT*NQ*NQ*KK + (size_t)q*KK*3;
        for (int k = 0; k < KK; ++k) {
            float best = -3.4e38f; int bi = 1 << 30;
#pragma unroll
            for (int jj = 0; jj < 4; ++jj)
                if (!(mask & (1u << jj)) && cv[jj] > best) { best = cv[jj]; bi = j0 + jj; }
#pragma unroll
            for (int m = 1; m <= 8; m <<= 1) {
                float ob = __shfl_xor(best, m, 64);
                int  obi = __shfl_xor(bi,  m, 64);
                if (ob > best || (ob == best && obi < bi)) { best = ob; bi = obi; }
            }
            if ((bi >> 2) == l16) mask |= 1u << (bi & 3);
            if (l16 == 0) {
                od[k] = d0[bi] + d1[bi];       // unbiased value
                int dh = (bi >> 3) - 4;
                int dw = (bi & 7) - 4;
                oi[k*3 + 0] = (float)t;
                oi[k*3 + 1] = (float)refl(qh + dh, HH);
                oi[k*3 + 2] = (float)refl(qxx*4 + dw, WW);
            }
        }
    }
}

extern "C" void kernel_launch(void* const* d_in, const int* in_sizes, int n_in,
                              void* d_out, int out_size, void* d_ws, size_t ws_size,
                              hipStream_t stream) {
    (void)in_sizes; (void)n_in; (void)d_ws; (void)ws_size; (void)out_size;
    const float* vid0 = (const float*)d_in[0];
    const float* vid1 = (const float*)d_in[1];
    float* out = (float*)d_out;
    nls_kernel<<<dim3(TT * NQ * (NQ / QPB)), dim3(256), 0, stream>>>(vid0, vid1, out);
}